// Round 1
// baseline (1080.780 us; speedup 1.0000x reference)
//
#include <hip/hip_runtime.h>

// Problem dims (fixed by the reference): B=2, H=16, L=S=2048, E=D=64.
// queries (d_in[0]) and keys (d_in[1]) are unused by the reference math.
constexpr int Bc = 2, Hc = 16, Lc = 2048, Sc = 2048, Dc = 64;
constexpr int TL = 16;   // rows (l) per block
constexpr int TJ = 128;  // j-tile width
constexpr int NT = 256;  // threads per block

__device__ __forceinline__ float wave_max(float v) {
#pragma unroll
  for (int m = 32; m >= 1; m >>= 1) v = fmaxf(v, __shfl_xor(v, m));
  return v;
}
__device__ __forceinline__ float wave_sum(float v) {
#pragma unroll
  for (int m = 32; m >= 1; m >>= 1) v += __shfl_xor(v, m);
  return v;
}

__global__ __launch_bounds__(NT) void zzy_attn(
    const float* __restrict__ values,   // [B,S,H,D]
    const float* __restrict__ scores,   // [B,H,L,S]
    float* __restrict__ out) {          // [B,L,H,D]
  const int lt = blockIdx.x, h = blockIdx.y, b = blockIdx.z;
  const int l0 = lt * TL;
  const int tid = threadIdx.x;

  __shared__ float s_m1[TL], s_iz1[TL], z2acc[TL];
  __shared__ float redbuf[NT / 64];
  __shared__ float vtile[TJ][Dc];   // 32 KB
  __shared__ float ptile[TL][TJ];   // 8 KB

  const size_t score_bh = (size_t)(b * Hc + h) * Lc * Sc;

  // ---- Phase 1: per-row first-softmax stats (m1, 1/Z1) over the FULL row ----
  for (int r = 0; r < TL; ++r) {
    const float4* row = (const float4*)(scores + score_bh + (size_t)(l0 + r) * Sc);
    float4 a = row[tid];
    float4 c = row[tid + NT];
    float lm = fmaxf(fmaxf(fmaxf(a.x, a.y), fmaxf(a.z, a.w)),
                     fmaxf(fmaxf(c.x, c.y), fmaxf(c.z, c.w)));
    float wm = wave_max(lm);
    __syncthreads();
    if ((tid & 63) == 0) redbuf[tid >> 6] = wm;
    __syncthreads();
    float m1 = fmaxf(fmaxf(redbuf[0], redbuf[1]), fmaxf(redbuf[2], redbuf[3]));
    float ls = __expf(a.x - m1) + __expf(a.y - m1) + __expf(a.z - m1) +
               __expf(a.w - m1) + __expf(c.x - m1) + __expf(c.y - m1) +
               __expf(c.z - m1) + __expf(c.w - m1);
    float ws = wave_sum(ls);
    __syncthreads();
    if ((tid & 63) == 0) redbuf[tid >> 6] = ws;
    __syncthreads();
    if (tid == 0) {
      float Z1 = redbuf[0] + redbuf[1] + redbuf[2] + redbuf[3];
      s_m1[r] = m1;
      s_iz1[r] = 1.0f / Z1;
    }
  }
  if (tid < TL) z2acc[tid] = 0.0f;
  __syncthreads();

  // ---- Phase 2: j-tiles; P = exp(first-softmax) masked; O += P @ V ----
  const int d  = tid & 63;   // output column
  const int rg = tid >> 6;   // row group 0..3 -> rows rg, rg+4, rg+8, rg+12
  float acc0 = 0.f, acc1 = 0.f, acc2 = 0.f, acc3 = 0.f;
  const float* vbase = values + (size_t)b * Sc * Hc * Dc + (size_t)h * Dc;
  const int ntiles = (l0 + TL - 1) / TJ + 1;  // causal: skip tiles above diag

  for (int jt = 0; jt < ntiles; ++jt) {
    const int j0 = jt * TJ;
    // stage V tile: v[j0+jj][d], 2048 float4 across 256 threads
#pragma unroll
    for (int e = 0; e < 8; ++e) {
      int f = tid + NT * e;
      int jj = f >> 4, dq = f & 15;
      float4 vv = *(const float4*)(vbase + (size_t)(j0 + jj) * (Hc * Dc) + dq * 4);
      *(float4*)&vtile[jj][dq * 4] = vv;
    }
    // P tile: p = exp( exp(s-m1)/Z1 ) for j<=l else 0  (2nd softmax numerator;
    // no max-shift needed since w in (0,1])
#pragma unroll
    for (int e = 0; e < 2; ++e) {
      int f = tid + NT * e;          // 0..511  (512 float4 = 16x128 floats)
      int r = f >> 5, jc4 = f & 31;
      int l = l0 + r;
      float4 s = *(const float4*)(scores + score_bh + (size_t)l * Sc + j0 + jc4 * 4);
      float m1 = s_m1[r], iz = s_iz1[r];
      int jb = j0 + jc4 * 4;
      float4 p;
      p.x = (jb + 0 <= l) ? __expf(__expf(s.x - m1) * iz) : 0.0f;
      p.y = (jb + 1 <= l) ? __expf(__expf(s.y - m1) * iz) : 0.0f;
      p.z = (jb + 2 <= l) ? __expf(__expf(s.z - m1) * iz) : 0.0f;
      p.w = (jb + 3 <= l) ? __expf(__expf(s.w - m1) * iz) : 0.0f;
      *(float4*)&ptile[r][jc4 * 4] = p;
    }
    __syncthreads();
    // Z2 partial sums (16 threads per row, shuffle-reduce within wave)
    {
      int r = tid >> 4, lane = tid & 15;
      float zp = 0.f;
#pragma unroll
      for (int k = 0; k < 8; ++k) zp += ptile[r][lane + 16 * k];
      zp += __shfl_xor(zp, 1);
      zp += __shfl_xor(zp, 2);
      zp += __shfl_xor(zp, 4);
      zp += __shfl_xor(zp, 8);
      if (lane == 0) z2acc[r] += zp;
    }
    // register-blocked VALU GEMM: 4 rows per thread share each v-read;
    // ptile reads are wave-broadcast, vtile reads are 2-way bank (free)
#pragma unroll 4
    for (int j = 0; j < TJ; ++j) {
      float vv = vtile[j][d];
      acc0 += ptile[rg][j] * vv;
      acc1 += ptile[rg + 4][j] * vv;
      acc2 += ptile[rg + 8][j] * vv;
      acc3 += ptile[rg + 12][j] * vv;
    }
    __syncthreads();
  }

  // ---- Epilogue: deferred 2nd-softmax normalization, coalesced store ----
  const float i0 = 1.0f / z2acc[rg];
  const float i1 = 1.0f / z2acc[rg + 4];
  const float i2 = 1.0f / z2acc[rg + 8];
  const float i3 = 1.0f / z2acc[rg + 12];
  out[((size_t)(b * Lc + l0 + rg) * Hc + h) * Dc + d]      = acc0 * i0;
  out[((size_t)(b * Lc + l0 + rg + 4) * Hc + h) * Dc + d]  = acc1 * i1;
  out[((size_t)(b * Lc + l0 + rg + 8) * Hc + h) * Dc + d]  = acc2 * i2;
  out[((size_t)(b * Lc + l0 + rg + 12) * Hc + h) * Dc + d] = acc3 * i3;
}

extern "C" void kernel_launch(void* const* d_in, const int* in_sizes, int n_in,
                              void* d_out, int out_size, void* d_ws,
                              size_t ws_size, hipStream_t stream) {
  // inputs: 0=queries (unused), 1=keys (unused), 2=values, 3=scores
  const float* values = (const float*)d_in[2];
  const float* scores = (const float*)d_in[3];
  float* out = (float*)d_out;
  dim3 grid(Lc / TL, Hc, Bc);
  zzy_attn<<<grid, NT, 0, stream>>>(values, scores, out);
}

// Round 2
// 750.002 us; speedup vs baseline: 1.4410x; 1.4410x over previous
//
#include <hip/hip_runtime.h>

// B=2, H=16, L=S=2048, E=D=64. queries/keys unused by the reference math.
constexpr int Bc = 2, Hc = 16, Lc = 2048, Sc = 2048, Dc = 64;
constexpr int TL = 16;    // rows per block
constexpr int TJ = 128;   // j-tile width
constexpr int NT = 256;   // threads per block
constexpr int PP = 136;   // ptile pitch (bf16 elems): 272 B -> 2-way bank alias (free)
constexpr int PV = 136;   // vT pitch

typedef __attribute__((ext_vector_type(8))) short short8;  // 8 bf16 (4 VGPRs)
typedef __attribute__((ext_vector_type(4))) float f32x4;

__device__ __forceinline__ unsigned short f2bf(float x) {
  unsigned u = __float_as_uint(x);
  u += 0x7FFF + ((u >> 16) & 1);   // RNE
  return (unsigned short)(u >> 16);
}
__device__ __forceinline__ float wave_max(float v) {
#pragma unroll
  for (int m = 32; m >= 1; m >>= 1) v = fmaxf(v, __shfl_xor(v, m));
  return v;
}
__device__ __forceinline__ float wave_sum(float v) {
#pragma unroll
  for (int m = 32; m >= 1; m >>= 1) v += __shfl_xor(v, m);
  return v;
}
__device__ __forceinline__ float half_sum(float v) {  // 32-lane halves
#pragma unroll
  for (int m = 16; m >= 1; m >>= 1) v += __shfl_xor(v, m);
  return v;
}

// V [B,S,H,D] fp32 -> Vt [B,H,D,S] bf16 (so main kernel reads V along j at fixed d)
__global__ __launch_bounds__(256) void transpose_v(const float* __restrict__ V,
                                                   unsigned short* __restrict__ Vt) {
  const int st = blockIdx.x, h = blockIdx.y, b = blockIdx.z;
  const int s0 = st * 64, tid = threadIdx.x;
  __shared__ float t[64][65];
  const float* vb = V + ((size_t)(b * Sc + s0) * Hc + h) * Dc;
#pragma unroll
  for (int e = 0; e < 4; ++e) {
    int f = tid + 256 * e, si = f >> 4, dq = f & 15;
    float4 v = *(const float4*)(vb + (size_t)si * Hc * Dc + dq * 4);
    t[si][dq * 4 + 0] = v.x; t[si][dq * 4 + 1] = v.y;
    t[si][dq * 4 + 2] = v.z; t[si][dq * 4 + 3] = v.w;
  }
  __syncthreads();
  const int d = tid >> 2, sq = tid & 3;
  unsigned pk[8];
#pragma unroll
  for (int k = 0; k < 8; ++k) {
    int s = sq * 16 + 2 * k;
    pk[k] = (unsigned)f2bf(t[s][d]) | ((unsigned)f2bf(t[s + 1][d]) << 16);
  }
  unsigned short* dst = Vt + ((size_t)((b * Hc + h) * Dc + d)) * Sc + s0 + sq * 16;
  uint4* dv = (uint4*)dst;
  dv[0] = make_uint4(pk[0], pk[1], pk[2], pk[3]);
  dv[1] = make_uint4(pk[4], pk[5], pk[6], pk[7]);
}

__global__ __launch_bounds__(NT) void zzy_attn(
    const unsigned short* __restrict__ Vt,  // [B,H,D,S] bf16
    const float* __restrict__ scores,       // [B,H,L,S] fp32
    float* __restrict__ out) {              // [B,L,H,D] fp32
  const int lt = blockIdx.x, h = blockIdx.y, b = blockIdx.z;
  const int l0 = lt * TL, tid = threadIdx.x;
  const int lane = tid & 63, wv = tid >> 6;

  __shared__ __align__(16) unsigned short vT[64 * PV];   // 17408 B
  __shared__ __align__(16) unsigned short pt[TL * PP];   //  4352 B
  __shared__ float s_m1[TL], s_iz1[TL], z2acc[TL];

  const size_t score_bh = (size_t)(b * Hc + h) * Lc * Sc;

  // ---- Phase 1: per-wave first-softmax stats over FULL rows (no barriers) ----
#pragma unroll
  for (int t = 0; t < 4; ++t) {
    const int r = wv * 4 + t;
    const float4* row = (const float4*)(scores + score_bh + (size_t)(l0 + r) * Sc);
    float4 v[8];
#pragma unroll
    for (int e = 0; e < 8; ++e) v[e] = row[lane + 64 * e];
    float m = -1e30f;
#pragma unroll
    for (int e = 0; e < 8; ++e)
      m = fmaxf(m, fmaxf(fmaxf(v[e].x, v[e].y), fmaxf(v[e].z, v[e].w)));
    m = wave_max(m);
    float s = 0.f;
#pragma unroll
    for (int e = 0; e < 8; ++e)
      s += __expf(v[e].x - m) + __expf(v[e].y - m) +
           __expf(v[e].z - m) + __expf(v[e].w - m);
    s = wave_sum(s);
    if (lane == 0) { s_m1[r] = m; s_iz1[r] = 1.0f / s; }
  }
  __syncthreads();

  // ---- Phase 2: j-tiles; P = exp(exp(s-m1)/Z1) masked; MFMA O += P @ V ----
  const int m16 = lane & 15, q = lane >> 4;
  f32x4 acc = {0.f, 0.f, 0.f, 0.f};
  float z0 = 0.f, z1 = 0.f;               // register Z2 partials (rows r0, r0+8)
  const int r0 = tid >> 5;
  const unsigned short* vtb = Vt + (size_t)((b * Hc + h) * Dc) * Sc;
  const int ntiles = (l0 + TL - 1) / TJ + 1;  // causal tile skip

  for (int jt = 0; jt < ntiles; ++jt) {
    const int j0 = jt * TJ;
    // stage V^T tile (row-major [d][j], b128 in/out)
#pragma unroll
    for (int e = 0; e < 4; ++e) {
      int f = tid + 256 * e, ch = f & 15, d = f >> 4;
      uint4 v = *(const uint4*)(vtb + (size_t)d * Sc + j0 + ch * 8);
      *(uint4*)&vT[d * PV + ch * 8] = v;
    }
    // P tile (bf16) + register Z2 accumulation
#pragma unroll
    for (int e = 0; e < 2; ++e) {
      int f = tid + 256 * e, r = f >> 5, jc = f & 31;
      int l = l0 + r;
      float4 s = *(const float4*)(scores + score_bh + (size_t)l * Sc + j0 + jc * 4);
      float m1 = s_m1[r], iz = s_iz1[r];
      int jb = j0 + jc * 4;
      float p0 = (jb + 0 <= l) ? __expf(__expf(s.x - m1) * iz) : 0.f;
      float p1 = (jb + 1 <= l) ? __expf(__expf(s.y - m1) * iz) : 0.f;
      float p2 = (jb + 2 <= l) ? __expf(__expf(s.z - m1) * iz) : 0.f;
      float p3 = (jb + 3 <= l) ? __expf(__expf(s.w - m1) * iz) : 0.f;
      if (e == 0) z0 += p0 + p1 + p2 + p3; else z1 += p0 + p1 + p2 + p3;
      uint2 pk;
      pk.x = (unsigned)f2bf(p0) | ((unsigned)f2bf(p1) << 16);
      pk.y = (unsigned)f2bf(p2) | ((unsigned)f2bf(p3) << 16);
      *(uint2*)&pt[r * PP + jc * 4] = pk;
    }
    __syncthreads();
    // MFMA: wave wv owns output cols 16*wv..16*wv+15; K=128 in 4 steps
#pragma unroll
    for (int ks = 0; ks < 4; ++ks) {
      short8 af = *(const short8*)&pt[m16 * PP + ks * 32 + q * 8];
      short8 bf = *(const short8*)&vT[(16 * wv + m16) * PV + ks * 32 + q * 8];
      acc = __builtin_amdgcn_mfma_f32_16x16x32_bf16(af, bf, acc, 0, 0, 0);
    }
    __syncthreads();
  }

  // ---- Z2 finalize: shuffle-reduce register partials, one write per row ----
  float zz0 = half_sum(z0), zz1 = half_sum(z1);
  if ((tid & 31) == 0) { z2acc[r0] = zz0; z2acc[r0 + 8] = zz1; }
  __syncthreads();

  // ---- Epilogue: C layout col=lane&15, row=q*4+reg; normalize and store ----
#pragma unroll
  for (int reg = 0; reg < 4; ++reg) {
    int row = q * 4 + reg;
    float o = acc[reg] / z2acc[row];
    out[((size_t)(b * Lc + l0 + row) * Hc + h) * Dc + 16 * wv + m16] = o;
  }
}

extern "C" void kernel_launch(void* const* d_in, const int* in_sizes, int n_in,
                              void* d_out, int out_size, void* d_ws,
                              size_t ws_size, hipStream_t stream) {
  // inputs: 0=queries (unused), 1=keys (unused), 2=values, 3=scores
  const float* values = (const float*)d_in[2];
  const float* scores = (const float*)d_in[3];
  float* out = (float*)d_out;
  unsigned short* Vt = (unsigned short*)d_ws;  // 8 MiB bf16 scratch

  transpose_v<<<dim3(Sc / 64, Hc, Bc), 256, 0, stream>>>(values, Vt);
  zzy_attn<<<dim3(Lc / TL, Hc, Bc), NT, 0, stream>>>(Vt, scores, out);
}